// Round 5
// baseline (819.883 us; speedup 1.0000x reference)
//
#include <hip/hip_runtime.h>

// R12: two changes, one theory: the VGPR cap was artificial.
// (a) R9 spilled at reg 129 under __launch_bounds__(512,2) (acts as 2
//     blocks/CU -> 4 waves/EU -> 128-reg cap). True occupancy is 1 block/CU
//     (8 waves, 2/EU): budget is 256. amdgpu_waves_per_eu(2,2) states it.
// (b) Spend the headroom on MB=32: 256 blocks = exactly 1/CU -> 130
//     sequential steps/CU instead of 260. Per-step fixed costs (barrier
//     drain, act tails, LDS latency) amortize over 2x MFMA work.
// Structure = R8-serial (rotation abandoned: R11 proved it net-negative).
// Per-phase M-tile split (mt=0 pass, mt=1 pass) keeps acc at 16 live regs:
// peak ~= 192 weights + 16 c + 16 acc + ~25 temps ~= 250 < 256.
// All weights back in registers (swi1h dropped). x staged in 25-step
// chunks (sxc 25.6KB, 4 refills/block ~1us total). LDS ~85KB.
// Tripwires: WRITE_SIZE must stay 1920KB (spill); VGPR_Count must
// EXCEED 128 (cap actually lifted).

typedef _Float16 half_t;
typedef _Float16 half8 __attribute__((ext_vector_type(8)));
typedef _Float16 half4 __attribute__((ext_vector_type(4)));
typedef float f32x4 __attribute__((ext_vector_type(4)));

#define SEQ 100
#define FUT 30
#define TOT (SEQ + FUT)
#define NIN 15
#define MB  32
#define CHK 25    // x-chunk steps staged at a time (100 = 4 chunks)
#define L2E 1.44269504f
#define SH  136   // h-tile row stride in halfs (272B = 17*16B: aligned, bank-spread)
#define SXS 20    // swx row stride in halfs (40B: conflict-free bank walk)
#define SXX 16    // sxc/sdec row stride in halfs (32B compact; 1 ax read/step ~4-way, noise)

#define MFMA32(A, B, C) __builtin_amdgcn_mfma_f32_16x16x32_f16((A), (B), (C), 0, 0, 0)
#define MFMA16(A, B, C) __builtin_amdgcn_mfma_f32_16x16x16f16((A), (B), (C), 0, 0, 0)

// ---- prep: fp16 repack, gate scales folded (i,f,o: -log2e ; cell g: +2log2e).
// n' = 64*wave + 16*gate + unit%16, unit j = 16*wave + (n&15), row = g*128 + j.
// ws halfword layout:
//   [0,      65536)  WH0[n*128+k]
//   [65536, 131072)  WI1[n*128+k]
//   [131072,196608)  WH1[n*128+k]
//   [196608,204800)  WX [n*16+k]   (k<15: w_ih0 ; k==15: scaled layer-0 bias)
//   [204800,206848)  BV: 1024 f32 = scaled (b_ih+b_hh), layer0 then layer1
__global__ void prep_kernel(const float* __restrict__ w_ih0, const float* __restrict__ w_hh0,
                            const float* __restrict__ b_ih0, const float* __restrict__ b_hh0,
                            const float* __restrict__ w_ih1, const float* __restrict__ w_hh1,
                            const float* __restrict__ b_ih1, const float* __restrict__ b_hh1,
                            half_t* __restrict__ wsh)
{
  int idx = blockIdx.x * 256 + threadIdx.x;
  if (idx < 196608) {
    int seg = idx >> 16;
    int r   = idx & 65535;
    int n   = r >> 7, k = r & 127;
    int g   = (n >> 4) & 3;
    int row = g * 128 + ((n >> 6) << 4) + (n & 15);
    float sc = (g == 2) ? (2.0f * L2E) : (-L2E);
    const float* src = (seg == 0) ? w_hh0 : ((seg == 1) ? w_ih1 : w_hh1);
    wsh[idx] = (half_t)(src[row * 128 + k] * sc);
  } else if (idx < 204800) {
    int r   = idx - 196608;
    int n   = r >> 4, k = r & 15;
    int g   = (n >> 4) & 3;
    int row = g * 128 + ((n >> 6) << 4) + (n & 15);
    float sc = (g == 2) ? (2.0f * L2E) : (-L2E);
    float v;
    if (k < NIN) v = w_ih0[row * NIN + k] * sc;
    else         v = (b_ih0[row] + b_hh0[row]) * sc;   // bias rides x[15]==1.0
    wsh[idx] = (half_t)v;
  } else if (idx < 205824) {
    int r     = idx - 204800;
    float* bv = (float*)(wsh + 204800);
    int which = r >> 9, n = r & 511;
    int g     = (n >> 4) & 3;
    int row   = g * 128 + ((n >> 6) << 4) + (n & 15);
    float sc  = (g == 2) ? (2.0f * L2E) : (-L2E);
    bv[r] = ((which == 0) ? (b_ih0[row] + b_hh0[row]) : (b_ih1[row] + b_hh1[row])) * sc;
  }
}

__global__ __attribute__((amdgpu_flat_work_group_size(512, 512)))
           __attribute__((amdgpu_waves_per_eu(2, 2)))
void lstm_kernel(const float* __restrict__ x,
                 const half_t* __restrict__ wsh,
                 const float* __restrict__ fcw,
                 const float* __restrict__ fcb,
                 float* __restrict__ out)
{
  __shared__ __align__(16) half_t sxc[CHK * MB * SXX];  // 25,600 B (x chunk)
  __shared__ __align__(16) half_t sh0[2][MB * SH];      // 17,408 B
  __shared__ __align__(16) half_t sh1[2][MB * SH];      // 17,408 B
  __shared__ __align__(16) half_t swx[512 * SXS];       // 20,480 B
  __shared__ __align__(16) half_t sdec[MB * SXX];       // 1,024 B
  __shared__ __align__(16) float  sbias[512];           // 2,048 B (layer-1 bias)
  __shared__ __align__(16) float  sfc[258];             // 1,032 B
  // total ~85 KB

  const half_t* WH0 = wsh;
  const half_t* WI1 = wsh + 65536;
  const half_t* WH1 = wsh + 131072;
  const half_t* WX  = wsh + 196608;
  const float*  BV  = (const float*)(wsh + 204800);

  const int tid   = threadIdx.x;
  const int wave  = tid >> 6;
  const int lane  = tid & 63;
  const int l16   = lane & 15;
  const int quad  = lane >> 4;
  const int nb    = wave * 64;
  const int bbase = blockIdx.x * MB;
  const int wcol  = wave * 16 + l16;   // h-store column for this lane

  // ---- persistent B-fragments: all recurrent weights resident (192 VGPRs) ----
  half8 wh0[4][4], wi1[4][4], wh1[4][4];  // [kt][g]
  #pragma unroll
  for (int kt = 0; kt < 4; ++kt) {
    #pragma unroll
    for (int g = 0; g < 4; ++g) {
      int n = nb + g * 16 + l16;
      int k = kt * 32 + quad * 8;
      wh0[kt][g] = *(const half8*)&WH0[n * 128 + k];
      wi1[kt][g] = *(const half8*)&WI1[n * 128 + k];
      wh1[kt][g] = *(const half8*)&WH1[n * 128 + k];
    }
  }

  // ---- one-time LDS staging ----
  for (int it = tid; it < 8192; it += 512) {
    int n = it >> 4, k = it & 15;
    swx[n * SXS + k] = WX[it];
  }
  for (int it = tid; it < 512; it += 512) sbias[it] = BV[512 + it];
  if (tid < 256) sfc[tid] = fcw[tid];
  if (tid < 2)   sfc[256 + tid] = fcb[tid];
  {
    int b = tid >> 4, i = tid & 15;   // 512 threads = 32 batches x 16 cols
    sdec[b * SXX + i] = (i < NIN) ? (half_t)x[(size_t)(bbase + b) * (SEQ * NIN) + 99 * NIN + i]
                                  : (half_t)1.0f;   // bias carrier
  }
  for (int it = tid; it < MB * SH; it += 512) {
    sh0[0][it] = (half_t)0; sh0[1][it] = (half_t)0;
    sh1[0][it] = (half_t)0; sh1[1][it] = (half_t)0;
  }
  __syncthreads();

  float c0[8] = {0.f, 0.f, 0.f, 0.f, 0.f, 0.f, 0.f, 0.f};
  float c1[8] = {0.f, 0.f, 0.f, 0.f, 0.f, 0.f, 0.f, 0.f};

  // fused activation (R6-verified): 5 exp2 + 2 rcp per element.
  // MT = M-tile (0/1); cell state CS[MT*4+r]; store row = MT*16+quad*4+r.
  #define ACT_STORE(ACC, CS, DST, MT)                                          \
    _Pragma("unroll")                                                          \
    for (int r = 0; r < 4; ++r) {                                              \
      float A  = __builtin_amdgcn_exp2f((ACC)[0][r]);                          \
      float C  = __builtin_amdgcn_exp2f((ACC)[1][r]);                          \
      float B  = __builtin_amdgcn_exp2f((ACC)[2][r]);                          \
      float D  = __builtin_amdgcn_exp2f((ACC)[3][r]);                          \
      float oA = 1.f + A, oB = 1.f + B, oC = 1.f + C, oD = 1.f + D;            \
      float P  = oA * oB;                                                      \
      float t  = (B - 1.f) * oC;                                               \
      float nm = fmaf((CS)[(MT) * 4 + r], P, t);                               \
      float rc = __builtin_amdgcn_rcpf(P * oC);                                \
      float cn = nm * rc;                                                      \
      (CS)[(MT) * 4 + r] = cn;                                                 \
      float E  = __builtin_amdgcn_exp2f(2.0f * L2E * cn);                      \
      float h  = (E - 1.f) * __builtin_amdgcn_rcpf(oD * (1.f + E));            \
      int   m  = (MT) * 16 + quad * 4 + r;                                     \
      (DST)[m * SH + wcol] = (half_t)h;                                        \
    }

  int cur = 0;
  for (int s = 0; s < TOT; ++s) {
    const int nxt = cur ^ 1;

    // ---- x-chunk refill (encoder, every CHK steps; ~1us total/block) ----
    if (s < SEQ && (s % CHK) == 0) {
      for (int it = tid; it < MB * CHK * NIN; it += 512) {
        int b  = it / (CHK * NIN);
        int r2 = it - b * (CHK * NIN);
        int sc = r2 / NIN;
        int i  = r2 - sc * NIN;
        sxc[(sc * MB + b) * SXX + i] =
            (half_t)x[(size_t)(bbase + b) * (SEQ * NIN) + (s + sc) * NIN + i];
      }
      for (int it = tid; it < CHK * MB; it += 512) sxc[it * SXX + 15] = (half_t)1.0f;
      __syncthreads();
    }
    const half_t* xsrc = (s < SEQ) ? &sxc[(s % CHK) * MB * SXX] : sdec;

    // ================= P0: layer 0 (two M-tile passes) =================
    #pragma unroll
    for (int mt = 0; mt < 2; ++mt) {
      f32x4 acc[4];
      #pragma unroll
      for (int g = 0; g < 4; ++g) acc[g] = (f32x4){0.f, 0.f, 0.f, 0.f};
      #pragma unroll
      for (int kt = 0; kt < 4; ++kt) {
        int c = kt * 4 + quad;
        half8 ah = *(const half8*)&sh0[cur][(mt * 16 + l16) * SH + c * 8];
        #pragma unroll
        for (int g = 0; g < 4; ++g) acc[g] = MFMA32(ah, wh0[kt][g], acc[g]);
      }
      // x contribution + layer-0 bias (WX col15 = bias, x col15 = 1)
      half4 ax = *(const half4*)&xsrc[(mt * 16 + l16) * SXX + quad * 4];
      #pragma unroll
      for (int g = 0; g < 4; ++g) {
        half4 bx = *(const half4*)&swx[(nb + g * 16 + l16) * SXS + quad * 4];
        acc[g] = MFMA16(ax, bx, acc[g]);
      }
      ACT_STORE(acc, c0, (&sh0[nxt][0]), mt)
    }
    __syncthreads();  // B1 (the only encoder barrier)

    // ================= P1: layer 1 (two M-tile passes) =================
    #pragma unroll
    for (int mt = 0; mt < 2; ++mt) {
      f32x4 acc[4];
      #pragma unroll
      for (int g = 0; g < 4; ++g) {
        float b = sbias[nb + g * 16 + l16];
        acc[g] = (f32x4){b, b, b, b};
      }
      #pragma unroll
      for (int kt = 0; kt < 4; ++kt) {
        int c = kt * 4 + quad;
        half8 ah = *(const half8*)&sh0[nxt][(mt * 16 + l16) * SH + c * 8];
        #pragma unroll
        for (int g = 0; g < 4; ++g) acc[g] = MFMA32(ah, wi1[kt][g], acc[g]);
      }
      #pragma unroll
      for (int kt = 0; kt < 4; ++kt) {
        int c = kt * 4 + quad;
        half8 ah = *(const half8*)&sh1[cur][(mt * 16 + l16) * SH + c * 8];
        #pragma unroll
        for (int g = 0; g < 4; ++g) acc[g] = MFMA32(ah, wh1[kt][g], acc[g]);
      }
      ACT_STORE(acc, c1, (&sh1[nxt][0]), mt)
    }

    // ================= decoder: FC + feedback =================
    if (s >= SEQ) {
      __syncthreads();  // B2d: h1_new visible
      {
        // 512 threads = 32 batches x 2 outs x 8 segs
        int b   = wave * 4 + (lane >> 4);
        int o   = (lane >> 3) & 1;
        int seg = lane & 7;
        float p = 0.f;
        #pragma unroll
        for (int cc = 0; cc < 2; ++cc) {
          int c = seg * 2 + cc;
          half8 hv = *(const half8*)&sh1[nxt][b * SH + c * 8];
          f32x4 w0 = *(const f32x4*)&sfc[o * 128 + c * 8];
          f32x4 w1 = *(const f32x4*)&sfc[o * 128 + c * 8 + 4];
          #pragma unroll
          for (int u = 0; u < 4; ++u) p = fmaf((float)hv[u], w0[u], p);
          #pragma unroll
          for (int u = 0; u < 4; ++u) p = fmaf((float)hv[4 + u], w1[u], p);
        }
        p += __shfl_down(p, 4);
        p += __shfl_down(p, 2);
        p += __shfl_down(p, 1);
        if (seg == 0) {
          p += sfc[256 + o];
          out[(size_t)(bbase + b) * (FUT * 2) + (s - SEQ) * 2 + o] = p;
          sdec[b * SXX + o] = (half_t)p;   // feed back into features 0:2
        }
      }
      __syncthreads();  // B3d: sdec feedback visible
    }

    cur = nxt;
  }
}

extern "C" void kernel_launch(void* const* d_in, const int* in_sizes, int n_in,
                              void* d_out, int out_size, void* d_ws, size_t ws_size,
                              hipStream_t stream)
{
  (void)in_sizes; (void)n_in; (void)out_size; (void)ws_size;
  const float* x     = (const float*)d_in[0];
  const float* w_ih0 = (const float*)d_in[1];
  const float* w_hh0 = (const float*)d_in[2];
  const float* b_ih0 = (const float*)d_in[3];
  const float* b_hh0 = (const float*)d_in[4];
  const float* w_ih1 = (const float*)d_in[5];
  const float* w_hh1 = (const float*)d_in[6];
  const float* b_ih1 = (const float*)d_in[7];
  const float* b_hh1 = (const float*)d_in[8];
  const float* fcw   = (const float*)d_in[9];
  const float* fcb   = (const float*)d_in[10];
  float*  out = (float*)d_out;
  half_t* wsh = (half_t*)d_ws;

  prep_kernel<<<(205824 + 255) / 256, 256, 0, stream>>>(
      w_ih0, w_hh0, b_ih0, b_hh0, w_ih1, w_hh1, b_ih1, b_hh1, wsh);
  lstm_kernel<<<8192 / MB, 512, 0, stream>>>(x, wsh, fcw, fcb, out);
}

// Round 6
// 592.012 us; speedup vs baseline: 1.3849x; 1.3849x over previous
//
#include <hip/hip_runtime.h>

// R13: deconfound R12. R12 failed two ways at once: amdgpu_waves_per_eu
// didn't lift the arch-VGPR cap (still 128) and the +16 c-state regs of
// MB=32 overflowed the real budget -> 43MB spill. Revised model: at
// 2 waves/EU the budget is 256 total/wave split 128 arch + 128 AGPR
// (rocprof shows the arch half only); R8's equilibrium had ~5-10 regs
// slack. R13 keeps the MB=32 amortization theory (256 blocks = 1/CU ->
// 130 steps/CU not 260; mt-pass interleave gives act||MFMA overlap with
// only 16 acc regs live) but restores __launch_bounds__(512,2) and
// demotes c-state to LDS (R11-proven: f32x4/thread slots, load at pass
// top under MFMAs, store after act) -- exactly the -16 arch regs that
// R12 overflowed by. LDS ~118KB.
// Tripwire: WRITE_SIZE must stay 1920KB; if spill -> MB=32 dead, R8 final.

typedef _Float16 half_t;
typedef _Float16 half8 __attribute__((ext_vector_type(8)));
typedef _Float16 half4 __attribute__((ext_vector_type(4)));
typedef float f32x4 __attribute__((ext_vector_type(4)));

#define SEQ 100
#define FUT 30
#define TOT (SEQ + FUT)
#define NIN 15
#define MB  32
#define CHK 25    // x-chunk steps staged at a time (100 = 4 chunks)
#define L2E 1.44269504f
#define SH  136   // h-tile row stride in halfs (272B = 17*16B: aligned, bank-spread)
#define SXS 20    // swx row stride in halfs (40B: conflict-free bank walk)
#define SXX 16    // sxc/sdec row stride in halfs (32B compact)

#define MFMA32(A, B, C) __builtin_amdgcn_mfma_f32_16x16x32_f16((A), (B), (C), 0, 0, 0)
#define MFMA16(A, B, C) __builtin_amdgcn_mfma_f32_16x16x16f16((A), (B), (C), 0, 0, 0)

// ---- prep: fp16 repack, gate scales folded (i,f,o: -log2e ; cell g: +2log2e).
// n' = 64*wave + 16*gate + unit%16, unit j = 16*wave + (n&15), row = g*128 + j.
// ws halfword layout:
//   [0,      65536)  WH0[n*128+k]
//   [65536, 131072)  WI1[n*128+k]
//   [131072,196608)  WH1[n*128+k]
//   [196608,204800)  WX [n*16+k]   (k<15: w_ih0 ; k==15: scaled layer-0 bias)
//   [204800,206848)  BV: 1024 f32 = scaled (b_ih+b_hh), layer0 then layer1
__global__ void prep_kernel(const float* __restrict__ w_ih0, const float* __restrict__ w_hh0,
                            const float* __restrict__ b_ih0, const float* __restrict__ b_hh0,
                            const float* __restrict__ w_ih1, const float* __restrict__ w_hh1,
                            const float* __restrict__ b_ih1, const float* __restrict__ b_hh1,
                            half_t* __restrict__ wsh)
{
  int idx = blockIdx.x * 256 + threadIdx.x;
  if (idx < 196608) {
    int seg = idx >> 16;
    int r   = idx & 65535;
    int n   = r >> 7, k = r & 127;
    int g   = (n >> 4) & 3;
    int row = g * 128 + ((n >> 6) << 4) + (n & 15);
    float sc = (g == 2) ? (2.0f * L2E) : (-L2E);
    const float* src = (seg == 0) ? w_hh0 : ((seg == 1) ? w_ih1 : w_hh1);
    wsh[idx] = (half_t)(src[row * 128 + k] * sc);
  } else if (idx < 204800) {
    int r   = idx - 196608;
    int n   = r >> 4, k = r & 15;
    int g   = (n >> 4) & 3;
    int row = g * 128 + ((n >> 6) << 4) + (n & 15);
    float sc = (g == 2) ? (2.0f * L2E) : (-L2E);
    float v;
    if (k < NIN) v = w_ih0[row * NIN + k] * sc;
    else         v = (b_ih0[row] + b_hh0[row]) * sc;   // bias rides x[15]==1.0
    wsh[idx] = (half_t)v;
  } else if (idx < 205824) {
    int r     = idx - 204800;
    float* bv = (float*)(wsh + 204800);
    int which = r >> 9, n = r & 511;
    int g     = (n >> 4) & 3;
    int row   = g * 128 + ((n >> 6) << 4) + (n & 15);
    float sc  = (g == 2) ? (2.0f * L2E) : (-L2E);
    bv[r] = ((which == 0) ? (b_ih0[row] + b_hh0[row]) : (b_ih1[row] + b_hh1[row])) * sc;
  }
}

__global__ __launch_bounds__(512, 2)
void lstm_kernel(const float* __restrict__ x,
                 const half_t* __restrict__ wsh,
                 const float* __restrict__ fcw,
                 const float* __restrict__ fcb,
                 float* __restrict__ out)
{
  __shared__ __align__(16) half_t sxc[CHK * MB * SXX];  // 25,600 B (x chunk)
  __shared__ __align__(16) half_t sh0[2][MB * SH];      // 17,408 B
  __shared__ __align__(16) half_t sh1[2][MB * SH];      // 17,408 B
  __shared__ __align__(16) half_t swx[512 * SXS];       // 20,480 B
  __shared__ __align__(16) half_t sdec[MB * SXX];       // 1,024 B
  __shared__ __align__(16) float  sbias[512];           // 2,048 B (layer-1 bias)
  __shared__ __align__(16) float  sfc[258];             // 1,032 B
  __shared__ __align__(16) float  sc0[2][512 * 4];      // 16,384 B cell L0 [mt][tid*4]
  __shared__ __align__(16) float  sc1[2][512 * 4];      // 16,384 B cell L1
  // total ~117.8 KB

  const half_t* WH0 = wsh;
  const half_t* WI1 = wsh + 65536;
  const half_t* WH1 = wsh + 131072;
  const half_t* WX  = wsh + 196608;
  const float*  BV  = (const float*)(wsh + 204800);

  const int tid   = threadIdx.x;
  const int wave  = tid >> 6;
  const int lane  = tid & 63;
  const int l16   = lane & 15;
  const int quad  = lane >> 4;
  const int nb    = wave * 64;
  const int bbase = blockIdx.x * MB;
  const int wcol  = wave * 16 + l16;   // h-store column for this lane

  // ---- persistent B-fragments: all recurrent weights resident (192 regs) ----
  half8 wh0[4][4], wi1[4][4], wh1[4][4];  // [kt][g]
  #pragma unroll
  for (int kt = 0; kt < 4; ++kt) {
    #pragma unroll
    for (int g = 0; g < 4; ++g) {
      int n = nb + g * 16 + l16;
      int k = kt * 32 + quad * 8;
      wh0[kt][g] = *(const half8*)&WH0[n * 128 + k];
      wi1[kt][g] = *(const half8*)&WI1[n * 128 + k];
      wh1[kt][g] = *(const half8*)&WH1[n * 128 + k];
    }
  }

  // ---- one-time LDS staging ----
  for (int it = tid; it < 8192; it += 512) {
    int n = it >> 4, k = it & 15;
    swx[n * SXS + k] = WX[it];
  }
  for (int it = tid; it < 512; it += 512) sbias[it] = BV[512 + it];
  if (tid < 256) sfc[tid] = fcw[tid];
  if (tid < 2)   sfc[256 + tid] = fcb[tid];
  {
    int b = tid >> 4, i = tid & 15;   // 512 threads = 32 batches x 16 cols
    sdec[b * SXX + i] = (i < NIN) ? (half_t)x[(size_t)(bbase + b) * (SEQ * NIN) + 99 * NIN + i]
                                  : (half_t)1.0f;   // bias carrier
  }
  for (int it = tid; it < MB * SH; it += 512) {
    sh0[0][it] = (half_t)0; sh0[1][it] = (half_t)0;
    sh1[0][it] = (half_t)0; sh1[1][it] = (half_t)0;
  }
  {
    f32x4 z = (f32x4){0.f, 0.f, 0.f, 0.f};
    *(f32x4*)&sc0[0][tid * 4] = z; *(f32x4*)&sc0[1][tid * 4] = z;
    *(f32x4*)&sc1[0][tid * 4] = z; *(f32x4*)&sc1[1][tid * 4] = z;
  }
  __syncthreads();

  // fused activation (R6-verified): 5 exp2 + 2 rcp per element.
  // CV = register f32x4 copy of this mt-pass's cell state.
  #define ACT_STORE(ACC, CV, DST, MT)                                          \
    _Pragma("unroll")                                                          \
    for (int r = 0; r < 4; ++r) {                                              \
      float A  = __builtin_amdgcn_exp2f((ACC)[0][r]);                          \
      float C  = __builtin_amdgcn_exp2f((ACC)[1][r]);                          \
      float B  = __builtin_amdgcn_exp2f((ACC)[2][r]);                          \
      float D  = __builtin_amdgcn_exp2f((ACC)[3][r]);                          \
      float oA = 1.f + A, oB = 1.f + B, oC = 1.f + C, oD = 1.f + D;            \
      float P  = oA * oB;                                                      \
      float t  = (B - 1.f) * oC;                                               \
      float nm = fmaf((CV)[r], P, t);                                          \
      float rc = __builtin_amdgcn_rcpf(P * oC);                                \
      float cn = nm * rc;                                                      \
      (CV)[r] = cn;                                                            \
      float E  = __builtin_amdgcn_exp2f(2.0f * L2E * cn);                      \
      float h  = (E - 1.f) * __builtin_amdgcn_rcpf(oD * (1.f + E));            \
      int   m  = (MT) * 16 + quad * 4 + r;                                     \
      (DST)[m * SH + wcol] = (half_t)h;                                        \
    }

  int cur = 0;
  for (int s = 0; s < TOT; ++s) {
    const int nxt = cur ^ 1;

    // ---- x-chunk refill (encoder, every CHK steps) ----
    if (s < SEQ && (s % CHK) == 0) {
      for (int it = tid; it < MB * CHK * NIN; it += 512) {
        int b  = it / (CHK * NIN);
        int r2 = it - b * (CHK * NIN);
        int sc = r2 / NIN;
        int i  = r2 - sc * NIN;
        sxc[(sc * MB + b) * SXX + i] =
            (half_t)x[(size_t)(bbase + b) * (SEQ * NIN) + (s + sc) * NIN + i];
      }
      for (int it = tid; it < CHK * MB; it += 512) sxc[it * SXX + 15] = (half_t)1.0f;
      __syncthreads();
    }
    const half_t* xsrc = (s < SEQ) ? &sxc[(s % CHK) * MB * SXX] : sdec;

    // ================= P0: layer 0 (two M-tile passes) =================
    #pragma unroll
    for (int mt = 0; mt < 2; ++mt) {
      f32x4 cv = *(const f32x4*)&sc0[mt][tid * 4];   // prefetch (hides under MFMAs)
      f32x4 acc[4];
      #pragma unroll
      for (int g = 0; g < 4; ++g) acc[g] = (f32x4){0.f, 0.f, 0.f, 0.f};
      #pragma unroll
      for (int kt = 0; kt < 4; ++kt) {
        int c = kt * 4 + quad;
        half8 ah = *(const half8*)&sh0[cur][(mt * 16 + l16) * SH + c * 8];
        #pragma unroll
        for (int g = 0; g < 4; ++g) acc[g] = MFMA32(ah, wh0[kt][g], acc[g]);
      }
      // x contribution + layer-0 bias (WX col15 = bias, x col15 = 1)
      half4 ax = *(const half4*)&xsrc[(mt * 16 + l16) * SXX + quad * 4];
      #pragma unroll
      for (int g = 0; g < 4; ++g) {
        half4 bx = *(const half4*)&swx[(nb + g * 16 + l16) * SXS + quad * 4];
        acc[g] = MFMA16(ax, bx, acc[g]);
      }
      ACT_STORE(acc, cv, (&sh0[nxt][0]), mt)
      *(f32x4*)&sc0[mt][tid * 4] = cv;
    }
    __syncthreads();  // B1 (the only encoder barrier)

    // ================= P1: layer 1 (two M-tile passes) =================
    #pragma unroll
    for (int mt = 0; mt < 2; ++mt) {
      f32x4 cv = *(const f32x4*)&sc1[mt][tid * 4];   // prefetch
      f32x4 acc[4];
      #pragma unroll
      for (int g = 0; g < 4; ++g) {
        float b = sbias[nb + g * 16 + l16];
        acc[g] = (f32x4){b, b, b, b};
      }
      #pragma unroll
      for (int kt = 0; kt < 4; ++kt) {
        int c = kt * 4 + quad;
        half8 ah = *(const half8*)&sh0[nxt][(mt * 16 + l16) * SH + c * 8];
        #pragma unroll
        for (int g = 0; g < 4; ++g) acc[g] = MFMA32(ah, wi1[kt][g], acc[g]);
      }
      #pragma unroll
      for (int kt = 0; kt < 4; ++kt) {
        int c = kt * 4 + quad;
        half8 ah = *(const half8*)&sh1[cur][(mt * 16 + l16) * SH + c * 8];
        #pragma unroll
        for (int g = 0; g < 4; ++g) acc[g] = MFMA32(ah, wh1[kt][g], acc[g]);
      }
      ACT_STORE(acc, cv, (&sh1[nxt][0]), mt)
      *(f32x4*)&sc1[mt][tid * 4] = cv;
    }

    // ================= decoder: FC + feedback =================
    if (s >= SEQ) {
      __syncthreads();  // B2d: h1_new visible
      {
        // 512 threads = 32 batches x 2 outs x 8 segs
        int b   = wave * 4 + (lane >> 4);
        int o   = (lane >> 3) & 1;
        int seg = lane & 7;
        float p = 0.f;
        #pragma unroll
        for (int cc = 0; cc < 2; ++cc) {
          int c = seg * 2 + cc;
          half8 hv = *(const half8*)&sh1[nxt][b * SH + c * 8];
          f32x4 w0 = *(const f32x4*)&sfc[o * 128 + c * 8];
          f32x4 w1 = *(const f32x4*)&sfc[o * 128 + c * 8 + 4];
          #pragma unroll
          for (int u = 0; u < 4; ++u) p = fmaf((float)hv[u], w0[u], p);
          #pragma unroll
          for (int u = 0; u < 4; ++u) p = fmaf((float)hv[4 + u], w1[u], p);
        }
        p += __shfl_down(p, 4);
        p += __shfl_down(p, 2);
        p += __shfl_down(p, 1);
        if (seg == 0) {
          p += sfc[256 + o];
          out[(size_t)(bbase + b) * (FUT * 2) + (s - SEQ) * 2 + o] = p;
          sdec[b * SXX + o] = (half_t)p;   // feed back into features 0:2
        }
      }
      __syncthreads();  // B3d: sdec feedback visible
    }

    cur = nxt;
  }
}

extern "C" void kernel_launch(void* const* d_in, const int* in_sizes, int n_in,
                              void* d_out, int out_size, void* d_ws, size_t ws_size,
                              hipStream_t stream)
{
  (void)in_sizes; (void)n_in; (void)out_size; (void)ws_size;
  const float* x     = (const float*)d_in[0];
  const float* w_ih0 = (const float*)d_in[1];
  const float* w_hh0 = (const float*)d_in[2];
  const float* b_ih0 = (const float*)d_in[3];
  const float* b_hh0 = (const float*)d_in[4];
  const float* w_ih1 = (const float*)d_in[5];
  const float* w_hh1 = (const float*)d_in[6];
  const float* b_ih1 = (const float*)d_in[7];
  const float* b_hh1 = (const float*)d_in[8];
  const float* fcw   = (const float*)d_in[9];
  const float* fcb   = (const float*)d_in[10];
  float*  out = (float*)d_out;
  half_t* wsh = (half_t*)d_ws;

  prep_kernel<<<(205824 + 255) / 256, 256, 0, stream>>>(
      w_ih0, w_hh0, b_ih0, b_hh0, w_ih1, w_hh1, b_ih1, b_hh1, wsh);
  lstm_kernel<<<8192 / MB, 512, 0, stream>>>(x, wsh, fcw, fcb, out);
}